// Round 1
// baseline (1336.120 us; speedup 1.0000x reference)
//
#include <hip/hip_runtime.h>

#define BB 64
#define TT 1024
#define CC 256

// One workgroup per batch chain (sequential in t). 1024 threads = 16 waves.
// Thread (grp = tid>>8, j = tid&255) holds W[grp*64+k][j] = exp(trans[b, grp*64+k, j])
// in 64 VGPRs. Per step: p = exp(alpha - m) (4 waves), register matvec (16 waves),
// LDS 4-way reduce, log + emission add, per-wave max folded into the write phase.
__global__ __launch_bounds__(1024, 4)
void crf_fwd(const float* __restrict__ emis,      // [B,T,C]
             const float* __restrict__ trans,     // [B,C,C]
             const int* __restrict__ seq_lens,    // [B]
             float* __restrict__ out_alpha,       // [B,T,C]
             float* __restrict__ out_logz)        // [B]
{
  const int b = blockIdx.x;
  const int tid = threadIdx.x;
  const int j = tid & (CC - 1);
  const int grp = tid >> 8;      // 0..3 : which 64-row slab of W
  const int lane = tid & 63;

  __shared__ float s_alpha[CC];
  __shared__ float s_p[CC];
  __shared__ float s_part[4][CC];
  __shared__ float s_last[CC];
  __shared__ float s_wmax[4];

  // ---- One-time: W slab into registers (coalesced across j per k) ----
  float W[64];
  const float* tb = trans + (size_t)b * CC * CC;
  #pragma unroll
  for (int k = 0; k < 64; ++k)
    W[k] = __expf(tb[(size_t)(grp * 64 + k) * CC + j]);

  const float* eb = emis + (size_t)b * TT * CC;
  float* ab = out_alpha + (size_t)b * TT * CC;
  const int L = seq_lens[b];

  // ---- t = 0 ----
  if (tid < CC) {
    float a0 = eb[j];
    s_alpha[j] = a0;
    ab[j] = a0;
    if (L == 1) s_last[j] = a0;
    float wm = a0;
    #pragma unroll
    for (int off = 32; off >= 1; off >>= 1)
      wm = fmaxf(wm, __shfl_xor(wm, off, 64));
    if (lane == 0) s_wmax[tid >> 6] = wm;
  }
  __syncthreads();

  // ---- main chain ----
  for (int t = 1; t < TT; ++t) {
    float e_t = 0.f, m = 0.f;
    if (tid < CC) {
      e_t = eb[(size_t)t * CC + j];   // prefetched; consumed after barrier B
      m = fmaxf(fmaxf(s_wmax[0], s_wmax[1]), fmaxf(s_wmax[2], s_wmax[3]));
      s_p[j] = __expf(s_alpha[j] - m);
    }
    __syncthreads();  // A: p ready

    // matvec partial: acc = sum_k p[grp*64+k] * W[k][j]
    float a0 = 0.f, a1 = 0.f, a2 = 0.f, a3 = 0.f;
    const float4* p4 = (const float4*)(s_p + grp * 64);
    #pragma unroll
    for (int k4 = 0; k4 < 16; ++k4) {
      float4 pv = p4[k4];              // wave-uniform broadcast read
      a0 = fmaf(pv.x, W[k4 * 4 + 0], a0);
      a1 = fmaf(pv.y, W[k4 * 4 + 1], a1);
      a2 = fmaf(pv.z, W[k4 * 4 + 2], a2);
      a3 = fmaf(pv.w, W[k4 * 4 + 3], a3);
    }
    s_part[grp][j] = (a0 + a1) + (a2 + a3);
    __syncthreads();  // B: partials ready

    if (tid < CC) {
      float s = (s_part[0][j] + s_part[1][j]) + (s_part[2][j] + s_part[3][j]);
      float anew = e_t + m + __logf(s);
      s_alpha[j] = anew;
      ab[(size_t)t * CC + j] = anew;
      if (t == L - 1) s_last[j] = anew;
      float wm = anew;                 // fold next step's max into this phase
      #pragma unroll
      for (int off = 32; off >= 1; off >>= 1)
        wm = fmaxf(wm, __shfl_xor(wm, off, 64));
      if (lane == 0) s_wmax[tid >> 6] = wm;
    }
    __syncthreads();  // C: alpha/wmax ready for next step
  }

  // ---- log_Z = logsumexp_j(s_last) by wave 0 ----
  if (tid < 64) {
    float4 v = ((const float4*)s_last)[lane];
    float m = fmaxf(fmaxf(v.x, v.y), fmaxf(v.z, v.w));
    #pragma unroll
    for (int off = 32; off >= 1; off >>= 1)
      m = fmaxf(m, __shfl_xor(m, off, 64));
    float s = __expf(v.x - m) + __expf(v.y - m) + __expf(v.z - m) + __expf(v.w - m);
    #pragma unroll
    for (int off = 32; off >= 1; off >>= 1)
      s += __shfl_xor(s, off, 64);
    if (lane == 0) out_logz[b] = m + __logf(s);
  }
}

extern "C" void kernel_launch(void* const* d_in, const int* in_sizes, int n_in,
                              void* d_out, int out_size, void* d_ws, size_t ws_size,
                              hipStream_t stream) {
  const float* emis = (const float*)d_in[0];
  const float* trans = (const float*)d_in[1];
  const int* seq_lens = (const int*)d_in[2];
  float* out_alpha = (float*)d_out;
  float* out_logz = out_alpha + (size_t)BB * TT * CC;
  hipLaunchKernelGGL(crf_fwd, dim3(BB), dim3(1024), 0, stream,
                     emis, trans, seq_lens, out_alpha, out_logz);
}